// Round 11
// baseline (55.995 us; speedup 1.0000x reference)
//
#include <hip/hip_runtime.h>

typedef __attribute__((ext_vector_type(8))) short bf16x8;
typedef __attribute__((ext_vector_type(16))) float f32x16;

#define LN 8192
#define SA_ROWB 4240          // bytes/shifted-copy row; 4240/16=265 ≡ 1 (mod 8) → bank spread
#define SB_OFF  33920         // B buffer starts after 8 A-rows (8*4240)
#define SMEM_BYTES 65536

__device__ __forceinline__ unsigned short f2bf(float f) {
    unsigned int u = __float_as_uint(f);
    u += 0x7fffu + ((u >> 16) & 1u);
    return (unsigned short)(u >> 16);
}
__device__ __forceinline__ float lrelu(float v) { return v > 0.f ? v : 0.01f * v; }
__device__ __forceinline__ float gldx(const float* p, int i) { return (i >= 0 && i < LN) ? p[i] : 0.f; }

// K1: ACF via 32x32x16 bf16 MFMA (round-10 verified, byte-identical)
__global__ __launch_bounds__(1024)
void acf_kernel(const float* __restrict__ x, float* __restrict__ ws)
{
    __shared__ __align__(16) unsigned char smem[SMEM_BYTES];
    __shared__ float red[16];

    const int tid  = threadIdx.x;
    const int row  = blockIdx.x;
    const int lane = tid & 63;
    const int wv   = tid >> 6;
    const float* xr = x + (size_t)row * LN;

    const int jj = lane & 31;
    const int gp = lane >> 5;
    const int dd = lane & 7;
    const int hh = (lane >> 3) & 3;
    const int aoff_lane = dd * SA_ROWB + 64 + 16 * gp - 16 * hh;

    const int q  = wv & 3;
    const int p  = wv >> 2;
    const int T1 = p;
    const int T2 = 7 - p;
    const int s1 = 512 - 64 * p;
    const int s2 = 64 + 64 * p;

    for (int s = tid; s < 1156; s += 1024) {
        const int e0 = s * 8;
        float4 fa, fb;
        if (e0 + 7 < LN) {
            fa = *(const float4*)(xr + e0);
            fb = *(const float4*)(xr + e0 + 4);
        } else {
            fa = make_float4(gldx(xr,e0),   gldx(xr,e0+1), gldx(xr,e0+2), gldx(xr,e0+3));
            fb = make_float4(gldx(xr,e0+4), gldx(xr,e0+5), gldx(xr,e0+6), gldx(xr,e0+7));
        }
        uint4 pk;
        pk.x = (unsigned)f2bf(fa.x) | ((unsigned)f2bf(fa.y) << 16);
        pk.y = (unsigned)f2bf(fa.z) | ((unsigned)f2bf(fa.w) << 16);
        pk.z = (unsigned)f2bf(fb.x) | ((unsigned)f2bf(fb.y) << 16);
        pk.w = (unsigned)f2bf(fb.z) | ((unsigned)f2bf(fb.w) << 16);
        const int ph = s ^ ((s >> 3) & 7);
        *(uint4*)(smem + SB_OFF + ph * 16) = pk;
    }

    f32x16 acc1 = {}, acc2 = {};

    for (int ch = 0; ch < 4; ++ch) {
        const int tc = ch << 11;
        __syncthreads();
        if (tid < 528) {
            const int base = tc + 4 * tid - 40;
            float4 fa, fb, fc;
            if (base >= 0 && base + 11 < LN) {
                fa = *(const float4*)(xr + base);
                fb = *(const float4*)(xr + base + 4);
                fc = *(const float4*)(xr + base + 8);
            } else {
                fa = make_float4(gldx(xr,base),   gldx(xr,base+1), gldx(xr,base+2),  gldx(xr,base+3));
                fb = make_float4(gldx(xr,base+4), gldx(xr,base+5), gldx(xr,base+6),  gldx(xr,base+7));
                fc = make_float4(gldx(xr,base+8), gldx(xr,base+9), gldx(xr,base+10), gldx(xr,base+11));
            }
            unsigned short us[12];
            us[0]=f2bf(fa.x); us[1]=f2bf(fa.y); us[2]=f2bf(fa.z);  us[3]=f2bf(fa.w);
            us[4]=f2bf(fb.x); us[5]=f2bf(fb.y); us[6]=f2bf(fb.z);  us[7]=f2bf(fb.w);
            us[8]=f2bf(fc.x); us[9]=f2bf(fc.y); us[10]=f2bf(fc.z); us[11]=f2bf(fc.w);
            #pragma unroll
            for (int d = 0; d < 8; ++d) {
                unsigned long long pk = (unsigned long long)us[8-d]
                                      | ((unsigned long long)us[9-d]  << 16)
                                      | ((unsigned long long)us[10-d] << 32)
                                      | ((unsigned long long)us[11-d] << 48);
                *(unsigned long long*)(smem + d * SA_ROWB + 8 * tid) = pk;
            }
        }
        __syncthreads();

        const int c0 = ch * 128;
        int dD = s2 - c0; dD = dD < 0 ? 0 : (dD > 128 ? 128 : dD);
        int sLo = c0 > s2 ? c0 : s2;
        int sHi = (c0 + 128) < s1 ? (c0 + 128) : s1;
        int sS = sHi - sLo; if (sS < 0) sS = 0;
        const int wd0 = c0 + q * (dD >> 2),  wd1 = c0 + (q + 1) * (dD >> 2);
        const int ws0 = sLo + q * (sS >> 2), ws1 = sLo + (q + 1) * (sS >> 2);

        {
            const unsigned char* ap = smem + aoff_lane + 32 * (wd0 - c0);
            int S1 = 128 * T1 + 2 * wd0 + 4 * jj + gp;
            int S2 = 128 * T2 + 2 * wd0 + 4 * jj + gp;
            for (int mq = wd0; mq < wd1; mq += 4) {
                bf16x8 A[4], B1[4], B2[4];
                #pragma unroll
                for (int u = 0; u < 4; ++u) {
                    A[u] = *(const bf16x8*)(ap + 32 * u);
                    const int sa = S1 + 2 * u, sb = S2 + 2 * u;
                    B1[u] = *(const bf16x8*)(smem + SB_OFF + ((sa ^ ((sa >> 3) & 7)) << 4));
                    B2[u] = *(const bf16x8*)(smem + SB_OFF + ((sb ^ ((sb >> 3) & 7)) << 4));
                }
                #pragma unroll
                for (int u = 0; u < 4; ++u) {
                    acc1 = __builtin_amdgcn_mfma_f32_32x32x16_bf16(A[u], B1[u], acc1, 0, 0, 0);
                    acc2 = __builtin_amdgcn_mfma_f32_32x32x16_bf16(A[u], B2[u], acc2, 0, 0, 0);
                }
                ap += 128; S1 += 8; S2 += 8;
            }
        }
        {
            const unsigned char* ap = smem + aoff_lane + 32 * (ws0 - c0);
            int S1 = 128 * T1 + 2 * ws0 + 4 * jj + gp;
            for (int mq = ws0; mq < ws1; mq += 4) {
                bf16x8 A[4], B1[4];
                #pragma unroll
                for (int u = 0; u < 4; ++u) {
                    A[u] = *(const bf16x8*)(ap + 32 * u);
                    const int sa = S1 + 2 * u;
                    B1[u] = *(const bf16x8*)(smem + SB_OFF + ((sa ^ ((sa >> 3) & 7)) << 4));
                }
                #pragma unroll
                for (int u = 0; u < 4; ++u)
                    acc1 = __builtin_amdgcn_mfma_f32_32x32x16_bf16(A[u], B1[u], acc1, 0, 0, 0);
                ap += 128; S1 += 8;
            }
        }
    }

    __syncthreads();

    auto pwrite = [&](int T, int s, const f32x16& acc, bool add) {
        unsigned char* bp = smem + (T * 2 + s) * 4096 + jj * 128;
        #pragma unroll
        for (int rq = 0; rq < 4; ++rq) {
            const int bi = (2 * rq + gp) ^ (jj & 7);
            float4 w = make_float4(acc[4*rq], acc[4*rq+1], acc[4*rq+2], acc[4*rq+3]);
            float4* pp = (float4*)(bp + bi * 16);
            if (add) { float4 o = *pp; w.x += o.x; w.y += o.y; w.z += o.z; w.w += o.w; }
            *pp = w;
        }
    };
    if (q < 2) { pwrite(T1, q, acc1, false); pwrite(T2, q, acc2, false); }
    __syncthreads();
    if (q >= 2) { pwrite(T1, q - 2, acc1, true); pwrite(T2, q - 2, acc2, true); }
    __syncthreads();

    {
        const int T  = tid >> 7;
        const int j2 = (tid >> 2) & 31;
        const int rq = tid & 3;
        const unsigned char* b0 = smem + (T * 2) * 4096 + j2 * 128;
        const int biA = (2 * rq)     ^ (j2 & 7);
        const int biB = (2 * rq + 1) ^ (j2 & 7);
        float4 s0a = *(const float4*)(b0 + biA * 16);
        float4 s0b = *(const float4*)(b0 + biB * 16);
        float4 s1a = *(const float4*)(b0 + 4096 + biA * 16);
        float4 s1b = *(const float4*)(b0 + 4096 + biB * 16);
        float v0 = s0a.x + s1a.x, v1 = s0a.y + s1a.y, v2 = s0a.z + s1a.z, v3 = s0a.w + s1a.w;
        float v4 = s0b.x + s1b.x, v5 = s0b.y + s1b.y, v6 = s0b.z + s1b.z, v7 = s0b.w + s1b.w;
        float m = fmaxf(fmaxf(fmaxf(v0, v1), fmaxf(v2, v3)), fmaxf(fmaxf(v4, v5), fmaxf(v6, v7)));

        float mx = m;
        for (int off = 32; off > 0; off >>= 1) mx = fmaxf(mx, __shfl_xor(mx, off));
        if (lane == 0) red[wv] = mx;
        __syncthreads();
        float pmax = red[0];
        #pragma unroll
        for (int k = 1; k < 16; ++k) pmax = fmaxf(pmax, red[k]);
        ws[(size_t)row * 1024 + tid] = m * (1.0f / pmax);
    }
}

// K2a: layer 1. 256 blocks = 16 row-groups(16 rows) x 16 neuron-slices(32 neurons).
// 1024 threads (16 waves); wave owns 2 neurons x 16 rows. Per-CU bytes 192KB.
__global__ __launch_bounds__(1024)
void mlp1_kernel(const float* __restrict__ ws, const float* __restrict__ W1,
                 const float* __restrict__ b1, float* __restrict__ h1g)
{
    __shared__ __align__(16) float arow[16 * 1024];   // 64KB
    const int tid  = threadIdx.x;
    const int lane = tid & 63;
    const int wv   = tid >> 6;          // 0..15
    const int bn   = blockIdx.x & 15;   // neuron slice
    const int rb   = blockIdx.x >> 4;   // row group

    const float4* src = (const float4*)(ws + (size_t)rb * 16384);
    float4* a4 = (float4*)arow;
    for (int i = tid; i < 4096; i += 1024) a4[i] = src[i];
    __syncthreads();

    const int n0 = bn * 32 + wv * 2;
    float acc0[16], acc1[16];
    #pragma unroll
    for (int r = 0; r < 16; ++r) { acc0[r] = 0.f; acc1[r] = 0.f; }

    const float4* w0p = (const float4*)(W1 + (size_t)n0 * 1024);
    const float4* w1p = (const float4*)(W1 + (size_t)(n0 + 1) * 1024);
    #pragma unroll
    for (int qq = 0; qq < 4; ++qq) {
        const int kq = lane + 64 * qq;
        float4 w0 = w0p[kq], w1 = w1p[kq];
        #pragma unroll
        for (int r = 0; r < 16; ++r) {
            float4 av = a4[r * 256 + kq];
            acc0[r] += w0.x*av.x + w0.y*av.y + w0.z*av.z + w0.w*av.w;
            acc1[r] += w1.x*av.x + w1.y*av.y + w1.z*av.z + w1.w*av.w;
        }
    }
    #pragma unroll
    for (int off = 32; off > 0; off >>= 1) {
        #pragma unroll
        for (int r = 0; r < 16; ++r) {
            acc0[r] += __shfl_xor(acc0[r], off);
            acc1[r] += __shfl_xor(acc1[r], off);
        }
    }

    if (lane == 0) {
        const float bb0 = b1[n0], bb1 = b1[n0 + 1];
        #pragma unroll
        for (int r = 0; r < 16; ++r) {
            float2 hv = make_float2(lrelu(acc0[r] + bb0), lrelu(acc1[r] + bb1));
            *(float2*)(h1g + (size_t)(rb * 16 + r) * 512 + n0) = hv;
        }
    }
}

// K2b: layers 2+3 row-per-block, 1024 threads (16 waves; 16 l2-neurons/wave)
__global__ __launch_bounds__(1024)
void mlp23_kernel(const float* __restrict__ h1g,
                  const float* __restrict__ W2, const float* __restrict__ b2,
                  const float* __restrict__ W3, const float* __restrict__ b3,
                  float* __restrict__ out)
{
    __shared__ __align__(16) float h1s[512];
    __shared__ __align__(16) float h2[256];
    const int tid  = threadIdx.x;
    const int lane = tid & 63;
    const int wv   = tid >> 6;          // 0..15
    const int row  = blockIdx.x;

    if (tid < 128) ((float4*)h1s)[tid] = ((const float4*)(h1g + (size_t)row * 512))[tid];
    __syncthreads();

    {
        const float4* a4 = (const float4*)h1s;
        float4 av0 = a4[lane], av1 = a4[lane + 64];
        #pragma unroll
        for (int n0 = 0; n0 < 16; n0 += 8) {
            const int nb = wv * 16 + n0;
            float s[8];
            #pragma unroll
            for (int u = 0; u < 8; ++u) {
                const float4* wr = (const float4*)(W2 + (size_t)(nb + u) * 512);
                float4 w0 = wr[lane], w1 = wr[lane + 64];
                float t0 = w0.x*av0.x + w0.y*av0.y + w0.z*av0.z + w0.w*av0.w;
                float t1 = w1.x*av1.x + w1.y*av1.y + w1.z*av1.z + w1.w*av1.w;
                s[u] = t0 + t1;
            }
            #pragma unroll
            for (int off = 32; off > 0; off >>= 1) {
                #pragma unroll
                for (int u = 0; u < 8; ++u) s[u] += __shfl_xor(s[u], off);
            }
            if (lane == 0) {
                #pragma unroll
                for (int u = 0; u < 8; ++u) h2[nb + u] = lrelu(s[u] + b2[nb + u]);
            }
        }
    }
    __syncthreads();

    if (wv < 4) {
        const float4 w = ((const float4*)(W3 + wv * 256))[lane];
        const float4 a = ((const float4*)h2)[lane];
        float s = w.x*a.x + w.y*a.y + w.z*a.z + w.w*a.w;
        for (int off = 32; off > 0; off >>= 1) s += __shfl_xor(s, off);
        if (lane == 0) out[row * 4 + wv] = s + b3[wv];
    }
}

extern "C" void kernel_launch(void* const* d_in, const int* in_sizes, int n_in,
                              void* d_out, int out_size, void* d_ws, size_t ws_size,
                              hipStream_t stream)
{
    const float* x  = (const float*)d_in[0];
    const float* W1 = (const float*)d_in[1];
    const float* b1 = (const float*)d_in[2];
    const float* W2 = (const float*)d_in[3];
    const float* b2 = (const float*)d_in[4];
    const float* W3 = (const float*)d_in[5];
    const float* b3 = (const float*)d_in[6];
    float* outp = (float*)d_out;
    float* wsn  = (float*)d_ws;                  // [0, 1MB): normalized features
    float* h1g  = wsn + 256 * 1024;              // [1MB, 1.5MB): h1 activations

    hipLaunchKernelGGL(acf_kernel,   dim3(256), dim3(1024), 0, stream, x, wsn);
    hipLaunchKernelGGL(mlp1_kernel,  dim3(256), dim3(1024), 0, stream, wsn, W1, b1, h1g);
    hipLaunchKernelGGL(mlp23_kernel, dim3(256), dim3(1024), 0, stream, h1g, W2, b2, W3, b3, outp);
}

// Round 12
// 49.842 us; speedup vs baseline: 1.1235x; 1.1235x over previous
//
#include <hip/hip_runtime.h>

typedef __attribute__((ext_vector_type(8))) short bf16x8;
typedef __attribute__((ext_vector_type(16))) float f32x16;

#define LN 8192
#define SA_ROWB 4240          // bytes/shifted-copy row; 4240/16=265 ≡ 1 (mod 8) → bank spread
#define SB_OFF  33920         // B buffer starts after 8 A-rows (8*4240)
#define SMEM_BYTES 65536

__device__ __forceinline__ unsigned short f2bf(float f) {
    unsigned int u = __float_as_uint(f);
    u += 0x7fffu + ((u >> 16) & 1u);
    return (unsigned short)(u >> 16);
}
__device__ __forceinline__ float lrelu(float v) { return v > 0.f ? v : 0.01f * v; }
__device__ __forceinline__ float gldx(const float* p, int i) { return (i >= 0 && i < LN) ? p[i] : 0.f; }

// accumulate dot of 8 bf16 weights (packed in uint4) with 8 f32 activations
__device__ __forceinline__ void dot8bf(uint4 q, const float* nl, float& acc) {
    acc += __uint_as_float(q.x << 16)          * nl[0];
    acc += __uint_as_float(q.x & 0xffff0000u)  * nl[1];
    acc += __uint_as_float(q.y << 16)          * nl[2];
    acc += __uint_as_float(q.y & 0xffff0000u)  * nl[3];
    acc += __uint_as_float(q.z << 16)          * nl[4];
    acc += __uint_as_float(q.z & 0xffff0000u)  * nl[5];
    acc += __uint_as_float(q.w << 16)          * nl[6];
    acc += __uint_as_float(q.w & 0xffff0000u)  * nl[7];
}

// K0: convert W1 (512x1024 fp32) -> bf16 into d_ws. Independent of acf.
__global__ __launch_bounds__(512)
void conv_kernel(const float* __restrict__ W1, unsigned short* __restrict__ W1bf)
{
    const int idx = blockIdx.x * 512 + threadIdx.x;   // 131072 float4s
    float4 v = ((const float4*)W1)[idx];
    ushort4 o;
    o.x = f2bf(v.x); o.y = f2bf(v.y); o.z = f2bf(v.z); o.w = f2bf(v.w);
    ((ushort4*)W1bf)[idx] = o;
}

// K1: fused ACF (round-10 verified math, byte-identical) + row-local MLP.
// Block owns row end-to-end: no cross-block dependency, no grid sync.
__global__ __launch_bounds__(1024)
void fused_kernel(const float* __restrict__ x,
                  const unsigned short* __restrict__ W1bf, const float* __restrict__ b1,
                  const float* __restrict__ W2, const float* __restrict__ b2,
                  const float* __restrict__ W3, const float* __restrict__ b3,
                  float* __restrict__ out)
{
    __shared__ __align__(16) unsigned char smem[SMEM_BYTES];
    __shared__ float red[16];

    const int tid  = threadIdx.x;
    const int row  = blockIdx.x;
    const int lane = tid & 63;
    const int wv   = tid >> 6;
    const float* xr = x + (size_t)row * LN;

    // ---------------- phase A: ACF (identical to round 10) ----------------
    const int jj = lane & 31;
    const int gp = lane >> 5;
    const int dd = lane & 7;
    const int hh = (lane >> 3) & 3;
    const int aoff_lane = dd * SA_ROWB + 64 + 16 * gp - 16 * hh;

    const int q  = wv & 3;
    const int p  = wv >> 2;
    const int T1 = p;
    const int T2 = 7 - p;
    const int s1 = 512 - 64 * p;
    const int s2 = 64 + 64 * p;

    for (int s = tid; s < 1156; s += 1024) {
        const int e0 = s * 8;
        float4 fa, fb;
        if (e0 + 7 < LN) {
            fa = *(const float4*)(xr + e0);
            fb = *(const float4*)(xr + e0 + 4);
        } else {
            fa = make_float4(gldx(xr,e0),   gldx(xr,e0+1), gldx(xr,e0+2), gldx(xr,e0+3));
            fb = make_float4(gldx(xr,e0+4), gldx(xr,e0+5), gldx(xr,e0+6), gldx(xr,e0+7));
        }
        uint4 pk;
        pk.x = (unsigned)f2bf(fa.x) | ((unsigned)f2bf(fa.y) << 16);
        pk.y = (unsigned)f2bf(fa.z) | ((unsigned)f2bf(fa.w) << 16);
        pk.z = (unsigned)f2bf(fb.x) | ((unsigned)f2bf(fb.y) << 16);
        pk.w = (unsigned)f2bf(fb.z) | ((unsigned)f2bf(fb.w) << 16);
        const int ph = s ^ ((s >> 3) & 7);
        *(uint4*)(smem + SB_OFF + ph * 16) = pk;
    }

    f32x16 acc1 = {}, acc2 = {};

    for (int ch = 0; ch < 4; ++ch) {
        const int tc = ch << 11;
        __syncthreads();
        if (tid < 528) {
            const int base = tc + 4 * tid - 40;
            float4 fa, fb, fc;
            if (base >= 0 && base + 11 < LN) {
                fa = *(const float4*)(xr + base);
                fb = *(const float4*)(xr + base + 4);
                fc = *(const float4*)(xr + base + 8);
            } else {
                fa = make_float4(gldx(xr,base),   gldx(xr,base+1), gldx(xr,base+2),  gldx(xr,base+3));
                fb = make_float4(gldx(xr,base+4), gldx(xr,base+5), gldx(xr,base+6),  gldx(xr,base+7));
                fc = make_float4(gldx(xr,base+8), gldx(xr,base+9), gldx(xr,base+10), gldx(xr,base+11));
            }
            unsigned short us[12];
            us[0]=f2bf(fa.x); us[1]=f2bf(fa.y); us[2]=f2bf(fa.z);  us[3]=f2bf(fa.w);
            us[4]=f2bf(fb.x); us[5]=f2bf(fb.y); us[6]=f2bf(fb.z);  us[7]=f2bf(fb.w);
            us[8]=f2bf(fc.x); us[9]=f2bf(fc.y); us[10]=f2bf(fc.z); us[11]=f2bf(fc.w);
            #pragma unroll
            for (int d = 0; d < 8; ++d) {
                unsigned long long pk = (unsigned long long)us[8-d]
                                      | ((unsigned long long)us[9-d]  << 16)
                                      | ((unsigned long long)us[10-d] << 32)
                                      | ((unsigned long long)us[11-d] << 48);
                *(unsigned long long*)(smem + d * SA_ROWB + 8 * tid) = pk;
            }
        }
        __syncthreads();

        const int c0 = ch * 128;
        int dD = s2 - c0; dD = dD < 0 ? 0 : (dD > 128 ? 128 : dD);
        int sLo = c0 > s2 ? c0 : s2;
        int sHi = (c0 + 128) < s1 ? (c0 + 128) : s1;
        int sS = sHi - sLo; if (sS < 0) sS = 0;
        const int wd0 = c0 + q * (dD >> 2),  wd1 = c0 + (q + 1) * (dD >> 2);
        const int ws0 = sLo + q * (sS >> 2), ws1 = sLo + (q + 1) * (sS >> 2);

        {
            const unsigned char* ap = smem + aoff_lane + 32 * (wd0 - c0);
            int S1 = 128 * T1 + 2 * wd0 + 4 * jj + gp;
            int S2 = 128 * T2 + 2 * wd0 + 4 * jj + gp;
            for (int mq = wd0; mq < wd1; mq += 4) {
                bf16x8 A[4], B1[4], B2[4];
                #pragma unroll
                for (int u = 0; u < 4; ++u) {
                    A[u] = *(const bf16x8*)(ap + 32 * u);
                    const int sa = S1 + 2 * u, sb = S2 + 2 * u;
                    B1[u] = *(const bf16x8*)(smem + SB_OFF + ((sa ^ ((sa >> 3) & 7)) << 4));
                    B2[u] = *(const bf16x8*)(smem + SB_OFF + ((sb ^ ((sb >> 3) & 7)) << 4));
                }
                #pragma unroll
                for (int u = 0; u < 4; ++u) {
                    acc1 = __builtin_amdgcn_mfma_f32_32x32x16_bf16(A[u], B1[u], acc1, 0, 0, 0);
                    acc2 = __builtin_amdgcn_mfma_f32_32x32x16_bf16(A[u], B2[u], acc2, 0, 0, 0);
                }
                ap += 128; S1 += 8; S2 += 8;
            }
        }
        {
            const unsigned char* ap = smem + aoff_lane + 32 * (ws0 - c0);
            int S1 = 128 * T1 + 2 * ws0 + 4 * jj + gp;
            for (int mq = ws0; mq < ws1; mq += 4) {
                bf16x8 A[4], B1[4];
                #pragma unroll
                for (int u = 0; u < 4; ++u) {
                    A[u] = *(const bf16x8*)(ap + 32 * u);
                    const int sa = S1 + 2 * u;
                    B1[u] = *(const bf16x8*)(smem + SB_OFF + ((sa ^ ((sa >> 3) & 7)) << 4));
                }
                #pragma unroll
                for (int u = 0; u < 4; ++u)
                    acc1 = __builtin_amdgcn_mfma_f32_32x32x16_bf16(A[u], B1[u], acc1, 0, 0, 0);
                ap += 128; S1 += 8;
            }
        }
    }

    __syncthreads();

    auto pwrite = [&](int T, int s, const f32x16& acc, bool add) {
        unsigned char* bp = smem + (T * 2 + s) * 4096 + jj * 128;
        #pragma unroll
        for (int rq = 0; rq < 4; ++rq) {
            const int bi = (2 * rq + gp) ^ (jj & 7);
            float4 w = make_float4(acc[4*rq], acc[4*rq+1], acc[4*rq+2], acc[4*rq+3]);
            float4* pp = (float4*)(bp + bi * 16);
            if (add) { float4 o = *pp; w.x += o.x; w.y += o.y; w.z += o.z; w.w += o.w; }
            *pp = w;
        }
    };
    if (q < 2) { pwrite(T1, q, acc1, false); pwrite(T2, q, acc2, false); }
    __syncthreads();
    if (q >= 2) { pwrite(T1, q - 2, acc1, true); pwrite(T2, q - 2, acc2, true); }
    __syncthreads();

    // ---- phase C: pool8 + rowmax + normalize -> LDS (nrm) ----
    float* nrm = (float*)smem;                 // [0, 4096)
    float* h1  = (float*)(smem + 4096);        // [4096, 6144)
    float* h2  = (float*)(smem + 6144);        // [6144, 7168)
    {
        const int T  = tid >> 7;
        const int j2 = (tid >> 2) & 31;
        const int rq = tid & 3;
        const unsigned char* b0 = smem + (T * 2) * 4096 + j2 * 128;
        const int biA = (2 * rq)     ^ (j2 & 7);
        const int biB = (2 * rq + 1) ^ (j2 & 7);
        float4 s0a = *(const float4*)(b0 + biA * 16);
        float4 s0b = *(const float4*)(b0 + biB * 16);
        float4 s1a = *(const float4*)(b0 + 4096 + biA * 16);
        float4 s1b = *(const float4*)(b0 + 4096 + biB * 16);
        float v0 = s0a.x + s1a.x, v1 = s0a.y + s1a.y, v2 = s0a.z + s1a.z, v3 = s0a.w + s1a.w;
        float v4 = s0b.x + s1b.x, v5 = s0b.y + s1b.y, v6 = s0b.z + s1b.z, v7 = s0b.w + s1b.w;
        float m = fmaxf(fmaxf(fmaxf(v0, v1), fmaxf(v2, v3)), fmaxf(fmaxf(v4, v5), fmaxf(v6, v7)));

        float mx = m;
        for (int off = 32; off > 0; off >>= 1) mx = fmaxf(mx, __shfl_xor(mx, off));
        if (lane == 0) red[wv] = mx;
        __syncthreads();            // all partial-buffer reads complete before this
        float pmax = red[0];
        #pragma unroll
        for (int k = 1; k < 16; ++k) pmax = fmaxf(pmax, red[k]);
        nrm[tid] = m * (1.0f / pmax);   // overlay write (safe: after barrier)
    }
    __syncthreads();

    // ---- phase D: layer 1 (bf16 weights), wave wv owns neurons [32wv, 32wv+32) ----
    {
        // lane-local activation slices: k = 8*lane .. +7 and 512+8*lane .. +7
        float nlo[8], nhi[8];
        {
            const float4* n4 = (const float4*)nrm;
            float4 a0 = n4[2 * lane], a1 = n4[2 * lane + 1];
            float4 b0 = n4[128 + 2 * lane], b1v = n4[128 + 2 * lane + 1];
            nlo[0]=a0.x; nlo[1]=a0.y; nlo[2]=a0.z; nlo[3]=a0.w;
            nlo[4]=a1.x; nlo[5]=a1.y; nlo[6]=a1.z; nlo[7]=a1.w;
            nhi[0]=b0.x; nhi[1]=b0.y; nhi[2]=b0.z; nhi[3]=b0.w;
            nhi[4]=b1v.x; nhi[5]=b1v.y; nhi[6]=b1v.z; nhi[7]=b1v.w;
        }
        for (int n0 = 0; n0 < 32; n0 += 4) {
            const int nb = wv * 32 + n0;
            float s0 = 0.f, s1 = 0.f, s2v = 0.f, s3 = 0.f;
            {
                const uint4* r0 = (const uint4*)(W1bf + (size_t)nb * 1024);
                const uint4* r1 = (const uint4*)(W1bf + (size_t)(nb + 1) * 1024);
                const uint4* r2 = (const uint4*)(W1bf + (size_t)(nb + 2) * 1024);
                const uint4* r3 = (const uint4*)(W1bf + (size_t)(nb + 3) * 1024);
                uint4 qa0 = r0[lane], qb0 = r0[64 + lane];
                uint4 qa1 = r1[lane], qb1 = r1[64 + lane];
                uint4 qa2 = r2[lane], qb2 = r2[64 + lane];
                uint4 qa3 = r3[lane], qb3 = r3[64 + lane];
                dot8bf(qa0, nlo, s0); dot8bf(qb0, nhi, s0);
                dot8bf(qa1, nlo, s1); dot8bf(qb1, nhi, s1);
                dot8bf(qa2, nlo, s2v); dot8bf(qb2, nhi, s2v);
                dot8bf(qa3, nlo, s3); dot8bf(qb3, nhi, s3);
            }
            #pragma unroll
            for (int off = 32; off > 0; off >>= 1) {
                s0 += __shfl_xor(s0, off);
                s1 += __shfl_xor(s1, off);
                s2v += __shfl_xor(s2v, off);
                s3 += __shfl_xor(s3, off);
            }
            if (lane == 0) {
                h1[nb]     = lrelu(s0 + b1[nb]);
                h1[nb + 1] = lrelu(s1 + b1[nb + 1]);
                h1[nb + 2] = lrelu(s2v + b1[nb + 2]);
                h1[nb + 3] = lrelu(s3 + b1[nb + 3]);
            }
        }
    }
    __syncthreads();

    // ---- phase E: layer 2 (fp32), wave wv owns neurons [16wv, 16wv+16) ----
    {
        const float4* a4 = (const float4*)h1;
        float4 av0 = a4[lane], av1 = a4[lane + 64];
        #pragma unroll
        for (int n0 = 0; n0 < 16; n0 += 8) {
            const int nb = wv * 16 + n0;
            float s[8];
            #pragma unroll
            for (int u = 0; u < 8; ++u) {
                const float4* wr = (const float4*)(W2 + (size_t)(nb + u) * 512);
                float4 w0 = wr[lane], w1 = wr[lane + 64];
                float t0 = w0.x*av0.x + w0.y*av0.y + w0.z*av0.z + w0.w*av0.w;
                float t1 = w1.x*av1.x + w1.y*av1.y + w1.z*av1.z + w1.w*av1.w;
                s[u] = t0 + t1;
            }
            #pragma unroll
            for (int off = 32; off > 0; off >>= 1) {
                #pragma unroll
                for (int u = 0; u < 8; ++u) s[u] += __shfl_xor(s[u], off);
            }
            if (lane == 0) {
                #pragma unroll
                for (int u = 0; u < 8; ++u) h2[nb + u] = lrelu(s[u] + b2[nb + u]);
            }
        }
    }
    __syncthreads();

    // ---- phase F: layer 3 ----
    if (wv < 4) {
        const float4 w = ((const float4*)(W3 + wv * 256))[lane];
        const float4 a = ((const float4*)h2)[lane];
        float s = w.x*a.x + w.y*a.y + w.z*a.z + w.w*a.w;
        for (int off = 32; off > 0; off >>= 1) s += __shfl_xor(s, off);
        if (lane == 0) out[row * 4 + wv] = s + b3[wv];
    }
}

extern "C" void kernel_launch(void* const* d_in, const int* in_sizes, int n_in,
                              void* d_out, int out_size, void* d_ws, size_t ws_size,
                              hipStream_t stream)
{
    const float* x  = (const float*)d_in[0];
    const float* W1 = (const float*)d_in[1];
    const float* b1 = (const float*)d_in[2];
    const float* W2 = (const float*)d_in[3];
    const float* b2 = (const float*)d_in[4];
    const float* W3 = (const float*)d_in[5];
    const float* b3 = (const float*)d_in[6];
    float* outp = (float*)d_out;
    unsigned short* W1bf = (unsigned short*)d_ws;   // 512x1024 bf16 = 1MB

    hipLaunchKernelGGL(conv_kernel,  dim3(256), dim3(512),  0, stream, W1, W1bf);
    hipLaunchKernelGGL(fused_kernel, dim3(256), dim3(1024), 0, stream,
                       x, W1bf, b1, W2, b2, W3, b3, outp);
}

// Round 13
// 45.673 us; speedup vs baseline: 1.2260x; 1.0913x over previous
//
#include <hip/hip_runtime.h>

typedef __attribute__((ext_vector_type(8))) short bf16x8;
typedef __attribute__((ext_vector_type(16))) float f32x16;

#define LN 8192
#define SA_ROWB 4240          // bytes/shifted-copy row; 4240/16=265 ≡ 1 (mod 8) → bank spread
#define SB_OFF  33920         // B buffer starts after 8 A-rows (8*4240)
#define SMEM_BYTES 65536

__device__ __forceinline__ unsigned short f2bf(float f) {
    unsigned int u = __float_as_uint(f);
    u += 0x7fffu + ((u >> 16) & 1u);
    return (unsigned short)(u >> 16);
}
__device__ __forceinline__ float lrelu(float v) { return v > 0.f ? v : 0.01f * v; }
__device__ __forceinline__ float gldx(const float* p, int i) { return (i >= 0 && i < LN) ? p[i] : 0.f; }

// dot of 8 packed bf16 weights (uint4) with 8 f32 activations
__device__ __forceinline__ void dot8bf(uint4 q, const float* nl, float& acc) {
    acc += __uint_as_float(q.x << 16)          * nl[0];
    acc += __uint_as_float(q.x & 0xffff0000u)  * nl[1];
    acc += __uint_as_float(q.y << 16)          * nl[2];
    acc += __uint_as_float(q.y & 0xffff0000u)  * nl[3];
    acc += __uint_as_float(q.z << 16)          * nl[4];
    acc += __uint_as_float(q.z & 0xffff0000u)  * nl[5];
    acc += __uint_as_float(q.w << 16)          * nl[6];
    acc += __uint_as_float(q.w & 0xffff0000u)  * nl[7];
}
__device__ __forceinline__ uint4 pack8(float4 a, float4 b) {
    uint4 pk;
    pk.x = (unsigned)f2bf(a.x) | ((unsigned)f2bf(a.y) << 16);
    pk.y = (unsigned)f2bf(a.z) | ((unsigned)f2bf(a.w) << 16);
    pk.z = (unsigned)f2bf(b.x) | ((unsigned)f2bf(b.y) << 16);
    pk.w = (unsigned)f2bf(b.z) | ((unsigned)f2bf(b.w) << 16);
    return pk;
}

// K0: reformat W1,W2 -> k-major packed bf16.
// W1p[kqq*512 + n] (kqq=0..127) holds W1[n][8kqq..8kqq+7]; W2p[kqq*256 + n] (kqq=0..63).
__global__ __launch_bounds__(256)
void conv_kernel(const float* __restrict__ W1, const float* __restrict__ W2,
                 uint4* __restrict__ W1p, uint4* __restrict__ W2p)
{
    const int b = blockIdx.x, t = threadIdx.x;
    if (b < 256) {
        const int g = b * 256 + t;          // 65536
        const int n = g >> 7, kqq = g & 127;
        const float4* src = (const float4*)(W1 + (size_t)n * 1024 + 8 * kqq);
        W1p[kqq * 512 + n] = pack8(src[0], src[1]);
    } else {
        const int g = (b - 256) * 256 + t;  // 16384
        const int n = g >> 6, kqq = g & 63;
        const float4* src = (const float4*)(W2 + (size_t)n * 512 + 8 * kqq);
        W2p[kqq * 256 + n] = pack8(src[0], src[1]);
    }
}

// K1: fused ACF (round-10 verified math, byte-identical) + row-local MLP
// (neuron-per-lane, no shuffle reduces).
__global__ __launch_bounds__(1024)
void fused_kernel(const float* __restrict__ x,
                  const uint4* __restrict__ W1p, const float* __restrict__ b1,
                  const uint4* __restrict__ W2p, const float* __restrict__ b2,
                  const float* __restrict__ W3, const float* __restrict__ b3,
                  float* __restrict__ out)
{
    __shared__ __align__(16) unsigned char smem[SMEM_BYTES];
    __shared__ float red[16];

    const int tid  = threadIdx.x;
    const int row  = blockIdx.x;
    const int lane = tid & 63;
    const int wv   = tid >> 6;
    const float* xr = x + (size_t)row * LN;

    // ---------------- phase A: ACF (identical to round 10) ----------------
    const int jj = lane & 31;
    const int gp = lane >> 5;
    const int dd = lane & 7;
    const int hh = (lane >> 3) & 3;
    const int aoff_lane = dd * SA_ROWB + 64 + 16 * gp - 16 * hh;

    const int q  = wv & 3;
    const int p  = wv >> 2;
    const int T1 = p;
    const int T2 = 7 - p;
    const int s1 = 512 - 64 * p;
    const int s2 = 64 + 64 * p;

    for (int s = tid; s < 1156; s += 1024) {
        const int e0 = s * 8;
        float4 fa, fb;
        if (e0 + 7 < LN) {
            fa = *(const float4*)(xr + e0);
            fb = *(const float4*)(xr + e0 + 4);
        } else {
            fa = make_float4(gldx(xr,e0),   gldx(xr,e0+1), gldx(xr,e0+2), gldx(xr,e0+3));
            fb = make_float4(gldx(xr,e0+4), gldx(xr,e0+5), gldx(xr,e0+6), gldx(xr,e0+7));
        }
        uint4 pk = pack8(fa, fb);
        const int ph = s ^ ((s >> 3) & 7);
        *(uint4*)(smem + SB_OFF + ph * 16) = pk;
    }

    f32x16 acc1 = {}, acc2 = {};

    for (int ch = 0; ch < 4; ++ch) {
        const int tc = ch << 11;
        __syncthreads();
        if (tid < 528) {
            const int base = tc + 4 * tid - 40;
            float4 fa, fb, fc;
            if (base >= 0 && base + 11 < LN) {
                fa = *(const float4*)(xr + base);
                fb = *(const float4*)(xr + base + 4);
                fc = *(const float4*)(xr + base + 8);
            } else {
                fa = make_float4(gldx(xr,base),   gldx(xr,base+1), gldx(xr,base+2),  gldx(xr,base+3));
                fb = make_float4(gldx(xr,base+4), gldx(xr,base+5), gldx(xr,base+6),  gldx(xr,base+7));
                fc = make_float4(gldx(xr,base+8), gldx(xr,base+9), gldx(xr,base+10), gldx(xr,base+11));
            }
            unsigned short us[12];
            us[0]=f2bf(fa.x); us[1]=f2bf(fa.y); us[2]=f2bf(fa.z);  us[3]=f2bf(fa.w);
            us[4]=f2bf(fb.x); us[5]=f2bf(fb.y); us[6]=f2bf(fb.z);  us[7]=f2bf(fb.w);
            us[8]=f2bf(fc.x); us[9]=f2bf(fc.y); us[10]=f2bf(fc.z); us[11]=f2bf(fc.w);
            #pragma unroll
            for (int d = 0; d < 8; ++d) {
                unsigned long long pk = (unsigned long long)us[8-d]
                                      | ((unsigned long long)us[9-d]  << 16)
                                      | ((unsigned long long)us[10-d] << 32)
                                      | ((unsigned long long)us[11-d] << 48);
                *(unsigned long long*)(smem + d * SA_ROWB + 8 * tid) = pk;
            }
        }
        __syncthreads();

        const int c0 = ch * 128;
        int dD = s2 - c0; dD = dD < 0 ? 0 : (dD > 128 ? 128 : dD);
        int sLo = c0 > s2 ? c0 : s2;
        int sHi = (c0 + 128) < s1 ? (c0 + 128) : s1;
        int sS = sHi - sLo; if (sS < 0) sS = 0;
        const int wd0 = c0 + q * (dD >> 2),  wd1 = c0 + (q + 1) * (dD >> 2);
        const int ws0 = sLo + q * (sS >> 2), ws1 = sLo + (q + 1) * (sS >> 2);

        {
            const unsigned char* ap = smem + aoff_lane + 32 * (wd0 - c0);
            int S1 = 128 * T1 + 2 * wd0 + 4 * jj + gp;
            int S2 = 128 * T2 + 2 * wd0 + 4 * jj + gp;
            for (int mq = wd0; mq < wd1; mq += 4) {
                bf16x8 A[4], B1[4], B2[4];
                #pragma unroll
                for (int u = 0; u < 4; ++u) {
                    A[u] = *(const bf16x8*)(ap + 32 * u);
                    const int sa = S1 + 2 * u, sb = S2 + 2 * u;
                    B1[u] = *(const bf16x8*)(smem + SB_OFF + ((sa ^ ((sa >> 3) & 7)) << 4));
                    B2[u] = *(const bf16x8*)(smem + SB_OFF + ((sb ^ ((sb >> 3) & 7)) << 4));
                }
                #pragma unroll
                for (int u = 0; u < 4; ++u) {
                    acc1 = __builtin_amdgcn_mfma_f32_32x32x16_bf16(A[u], B1[u], acc1, 0, 0, 0);
                    acc2 = __builtin_amdgcn_mfma_f32_32x32x16_bf16(A[u], B2[u], acc2, 0, 0, 0);
                }
                ap += 128; S1 += 8; S2 += 8;
            }
        }
        {
            const unsigned char* ap = smem + aoff_lane + 32 * (ws0 - c0);
            int S1 = 128 * T1 + 2 * ws0 + 4 * jj + gp;
            for (int mq = ws0; mq < ws1; mq += 4) {
                bf16x8 A[4], B1[4];
                #pragma unroll
                for (int u = 0; u < 4; ++u) {
                    A[u] = *(const bf16x8*)(ap + 32 * u);
                    const int sa = S1 + 2 * u;
                    B1[u] = *(const bf16x8*)(smem + SB_OFF + ((sa ^ ((sa >> 3) & 7)) << 4));
                }
                #pragma unroll
                for (int u = 0; u < 4; ++u)
                    acc1 = __builtin_amdgcn_mfma_f32_32x32x16_bf16(A[u], B1[u], acc1, 0, 0, 0);
                ap += 128; S1 += 8;
            }
        }
    }

    __syncthreads();

    auto pwrite = [&](int T, int s, const f32x16& acc, bool add) {
        unsigned char* bp = smem + (T * 2 + s) * 4096 + jj * 128;
        #pragma unroll
        for (int rq = 0; rq < 4; ++rq) {
            const int bi = (2 * rq + gp) ^ (jj & 7);
            float4 w = make_float4(acc[4*rq], acc[4*rq+1], acc[4*rq+2], acc[4*rq+3]);
            float4* pp = (float4*)(bp + bi * 16);
            if (add) { float4 o = *pp; w.x += o.x; w.y += o.y; w.z += o.z; w.w += o.w; }
            *pp = w;
        }
    };
    if (q < 2) { pwrite(T1, q, acc1, false); pwrite(T2, q, acc2, false); }
    __syncthreads();
    if (q >= 2) { pwrite(T1, q - 2, acc1, true); pwrite(T2, q - 2, acc2, true); }
    __syncthreads();

    // LDS overlay for MLP phases (all after the barrier above)
    float* nrm = (float*)smem;                   // [0, 4096)
    float* h1  = (float*)(smem + 4096);          // [4096, 6144)
    float* h2  = (float*)(smem + 6144);          // [6144, 7168)
    float* ph  = (float*)(smem + 7168);          // [7168, 9216)   layer-1 K-half partials
    float* pe  = (float*)(smem + 9216);          // [9216, 12288)  layer-2 K-quarter partials

    // ---- phase C: pool8 + rowmax + normalize -> nrm ----
    {
        const int T  = tid >> 7;
        const int j2 = (tid >> 2) & 31;
        const int rq = tid & 3;
        const unsigned char* b0 = smem + (T * 2) * 4096 + j2 * 128;
        const int biA = (2 * rq)     ^ (j2 & 7);
        const int biB = (2 * rq + 1) ^ (j2 & 7);
        float4 s0a = *(const float4*)(b0 + biA * 16);
        float4 s0b = *(const float4*)(b0 + biB * 16);
        float4 s1a = *(const float4*)(b0 + 4096 + biA * 16);
        float4 s1b = *(const float4*)(b0 + 4096 + biB * 16);
        float v0 = s0a.x + s1a.x, v1 = s0a.y + s1a.y, v2 = s0a.z + s1a.z, v3 = s0a.w + s1a.w;
        float v4 = s0b.x + s1b.x, v5 = s0b.y + s1b.y, v6 = s0b.z + s1b.z, v7 = s0b.w + s1b.w;
        float m = fmaxf(fmaxf(fmaxf(v0, v1), fmaxf(v2, v3)), fmaxf(fmaxf(v4, v5), fmaxf(v6, v7)));

        float mx = m;
        for (int off = 32; off > 0; off >>= 1) mx = fmaxf(mx, __shfl_xor(mx, off));
        if (lane == 0) red[wv] = mx;
        __syncthreads();            // all partial-buffer reads complete before this
        float pmax = red[0];
        #pragma unroll
        for (int k = 1; k < 16; ++k) pmax = fmaxf(pmax, red[k]);
        nrm[tid] = m * (1.0f / pmax);
    }
    __syncthreads();

    // ---- phase D: layer 1, neuron-per-lane; thread = (neuron n, K-half kh) ----
    {
        const int n  = tid & 511;
        const int kh = tid >> 9;                 // 0 or 1
        const float4* n4 = (const float4*)nrm;
        const uint4* wp = W1p + (size_t)kh * 64 * 512 + n;
        float acc = 0.f;
        #pragma unroll 8
        for (int kq = 0; kq < 64; ++kq) {
            uint4 qw = wp[kq * 512];
            float4 a = n4[kh * 128 + 2 * kq];
            float4 b = n4[kh * 128 + 2 * kq + 1];
            float nl[8] = {a.x, a.y, a.z, a.w, b.x, b.y, b.z, b.w};
            dot8bf(qw, nl, acc);
        }
        if (kh == 1) ph[n] = acc;
        __syncthreads();
        if (kh == 0) h1[n] = lrelu(acc + ph[n] + b1[n]);
    }
    __syncthreads();

    // ---- phase E: layer 2, neuron-per-lane; thread = (neuron n, K-quarter qd) ----
    {
        const int n  = tid & 255;
        const int qd = tid >> 8;                 // 0..3
        const float4* h4 = (const float4*)h1;
        const uint4* wp = W2p + (size_t)qd * 16 * 256 + n;
        float acc = 0.f;
        #pragma unroll
        for (int kq = 0; kq < 16; ++kq) {
            uint4 qw = wp[kq * 256];
            float4 a = h4[qd * 32 + 2 * kq];
            float4 b = h4[qd * 32 + 2 * kq + 1];
            float nl[8] = {a.x, a.y, a.z, a.w, b.x, b.y, b.z, b.w};
            dot8bf(qw, nl, acc);
        }
        if (qd > 0) pe[(qd - 1) * 256 + n] = acc;
        __syncthreads();
        if (qd == 0) h2[n] = lrelu(acc + pe[n] + pe[256 + n] + pe[512 + n] + b2[n]);
    }
    __syncthreads();

    // ---- phase F: layer 3 ----
    if (wv < 4) {
        const float4 w = ((const float4*)(W3 + wv * 256))[lane];
        const float4 a = ((const float4*)h2)[lane];
        float s = w.x*a.x + w.y*a.y + w.z*a.z + w.w*a.w;
        for (int off = 32; off > 0; off >>= 1) s += __shfl_xor(s, off);
        if (lane == 0) out[row * 4 + wv] = s + b3[wv];
    }
}

extern "C" void kernel_launch(void* const* d_in, const int* in_sizes, int n_in,
                              void* d_out, int out_size, void* d_ws, size_t ws_size,
                              hipStream_t stream)
{
    const float* x  = (const float*)d_in[0];
    const float* W1 = (const float*)d_in[1];
    const float* b1 = (const float*)d_in[2];
    const float* W2 = (const float*)d_in[3];
    const float* b2 = (const float*)d_in[4];
    const float* W3 = (const float*)d_in[5];
    const float* b3 = (const float*)d_in[6];
    float* outp = (float*)d_out;
    uint4* W1p = (uint4*)d_ws;                          // 1MB (65536 uint4)
    uint4* W2p = (uint4*)((char*)d_ws + (1 << 20));     // 256KB (16384 uint4)

    hipLaunchKernelGGL(conv_kernel,  dim3(320), dim3(256),  0, stream, W1, W2, W1p, W2p);
    hipLaunchKernelGGL(fused_kernel, dim3(256), dim3(1024), 0, stream,
                       x, W1p, b1, W2p, b2, W3, b3, outp);
}